// Round 7
// baseline (283.782 us; speedup 1.0000x reference)
//
#include <hip/hip_runtime.h>
#include <hip/hip_bf16.h>

typedef __hip_bfloat16 bf16;
typedef short bf16x8_t __attribute__((ext_vector_type(8)));  // 8 bf16 = 4 VGPRs
typedef short s4_t __attribute__((ext_vector_type(4)));      // 4 bf16 = 8B
typedef float f32x4_t __attribute__((ext_vector_type(4)));

#define NTOK 8192
#define INF  1024
#define OUTF 1024
#define GS   8
#define KTOT (INF + INF * GS)  // 9216

union b8u { bf16 h[8]; bf16x8_t v; };
union b4u { bf16 h[4]; ushort2 v2[2]; };
union b4s { bf16 h[4]; s4_t v; };

// ---------------- fused prep (R3/R6 version VERBATIM — measured good) --------------
#define PA ((NTOK * INF / 4) / 256)   // 8192 blocks
#define PB ((OUTF * INF * 2) / 256)   // 8192 blocks

__global__ __launch_bounds__(256) void prep_fused(const float* __restrict__ x,
                                                  const float* __restrict__ bw,
                                                  const float* __restrict__ sw,
                                                  const float* __restrict__ ss,
                                                  bf16* __restrict__ A,
                                                  bf16* __restrict__ B) {
  const int b = blockIdx.x;
  if (b < PA) {
    const float EG[8]  = {0.36787944f, 0.47236655f, 0.60653066f, 0.77880078f,
                          1.0f, 1.28402542f, 1.64872127f, 2.11700002f};   // e^{g_v}
    const float EIG[8] = {2.71828183f, 2.11700002f, 1.64872127f, 1.28402542f,
                          1.0f, 0.77880078f, 0.60653066f, 0.47236655f};   // e^{-g_v}
    const int tid = b * 256 + threadIdx.x;      // 0 .. NTOK*INF/4-1
    const int qi = tid & 255;                   // i-quad within row; i = qi*4+j
    const int n = tid >> 8;
    const float4 x4 = ((const float4*)x)[tid];  // x[n*INF + qi*4 ..+3]
    const float xf[4] = {x4.x, x4.y, x4.z, x4.w};
    b4s sil;
    b8u kn[4];
    #pragma unroll
    for (int j = 0; j < 4; ++j) {
      const float xv = xf[j];
      const float en = __expf(-xv);
      const float ep = __expf(xv);
      sil.h[j] = __float2bfloat16(xv / (1.0f + en));   // SiLU
      #pragma unroll
      for (int g = 0; g < 8; ++g)
        kn[j].h[g] = __float2bfloat16(fminf(en * EG[g], ep * EIG[g]));
    }
    const size_t rowb = (size_t)n * KTOT;
    *(s4_t*)(A + rowb + qi * 4) = sil.v;                       // 8B aligned
    #pragma unroll
    for (int j = 0; j < 4; ++j)                                 // 4x16B contiguous
      *(bf16x8_t*)(A + rowb + INF + (size_t)(qi * 4 + j) * 8) = kn[j].v;
  } else {
    const int tid = (b - PA) * 256 + threadIdx.x;  // 0 .. OUTF*INF*2-1
    const int o = tid >> 11;
    const int r = tid & 2047;
    const float4 w4 = ((const float4*)sw)[tid];
    const float sc = ss[tid >> 1];
    b4u r4;
    r4.h[0] = __float2bfloat16(w4.x * sc);
    r4.h[1] = __float2bfloat16(w4.y * sc);
    r4.h[2] = __float2bfloat16(w4.z * sc);
    r4.h[3] = __float2bfloat16(w4.w * sc);
    const size_t rowb = (size_t)o * KTOT;
    *(ushort2*)(B + rowb + INF + (size_t)r * 4)     = r4.v2[0];
    *(ushort2*)(B + rowb + INF + (size_t)r * 4 + 2) = r4.v2[1];
    if ((tid & 1) == 0)
      B[rowb + (r >> 1)] = __float2bfloat16(bw[tid >> 1]);
  }
}

// ---------------- GEMM: C[M,N] = A[M,K] * B[N,K]^T ---------------------------------
// R6 base (1-barrier/K-tile, counted lgkm+vmcnt, 3-ring, XCD remap; 157us/985TF) with
// ONE structural change: k-slice-split wave pairs.
//   old: 8 waves x (64x64 tile, both k-slices) -> 16 ds_read_b128/wave/tile = 128KB/CU
//   new: 4 quadrants (128x64) x 2 k-slices; wave w: quadrant w&3, slice w>>2
//        -> 12 ds_read_b128/wave/tile (8 A + 4 B, ONE slice) = 96KB/CU  (-25% LDS
//        reads, the measured bottleneck). acc[8][4]; MFMA clusters of 16+16 with
//        i-split read groups (8+4). Pairs merge partial sums via LDS at epilogue
//        (one-time 128KB, reuses the ring).
// Sync ledger (per iter, unchanged from R6 where not noted):
//   - reads(cur) all lgkm-retired before boundary barrier (lgkm(0) precedes MFMA
//     cluster 2; no reads after). Stages(pb) overwrite tile kt-1's buffer whose
//     reads retired at iter kt-1's lgkm(0), before its barrier. SAFE.
//   - lgkm(4): wave issued exactly 12 ds_reads this iter (group0=8 oldest pinned
//     by sched_barrier); <=4 outstanding => group0 retired.
//   - boundary vmcnt(6): 6 newest = this iter's stages; tile kt+1's 6 older ->
//     retired. Tail: vmcnt(0).
//   - epilogue: loop exits via barrier w/ vmcnt(0)+lgkm(0) drain; s=1 waves write
//     smem, full barrier, s=0 waves read+add+store. Barriers at top level (uniform).
#define BM 256
#define BN 128
#define BK 64
#define NT (KTOT / BK)            // 144
#define LDSA (BM * BK * 2)        // 32768 B
#define LDSB (BN * BK * 2)        // 16384 B
#define LDSBUF (LDSA + LDSB)      // 49152 B

__global__ __launch_bounds__(512) void gemm_bt2(const bf16* __restrict__ A,
                                                const bf16* __restrict__ B,
                                                float* __restrict__ C) {
  __shared__ __align__(16) char smem[3 * LDSBUF];   // 144 KB ring (+epilogue merge)
  const int t = threadIdx.x;
  const int lane = t & 63;
  const int w = t >> 6;            // wave 0..7
  const int q = w & 3;             // quadrant 0..3 (2M x 2N of 128x64)
  const int s = w >> 2;            // k-slice 0/1 (kk = s*32)
  const int wm = (q >> 1) * 128;   // 0,128
  const int wn = (q & 1) * 64;     // 0,64
  // XCD-aware remap (bijective on 0..255): xcd = lid&7 gets br 4*xcd..4*xcd+3, all bc.
  const int lid = blockIdx.y * 8 + blockIdx.x;     // linear id, x fastest
  const int br = (lid & 7) * 4 + ((lid >> 3) & 3); // M tile (0..31)
  const int bc = lid >> 5;                         // N tile (0..7)

  const int srow = t >> 3;                         // 0..63
  const int scol = ((t & 7) ^ (srow & 7)) * 8;     // swizzled source k-offset (elems)
  const bf16* gA = A + (size_t)(br * BM + srow) * KTOT + scol;
  const bf16* gB = B + (size_t)(bc * BN + srow) * KTOT + scol;
  const int wb = w * 1024;                         // wave's 64 lanes x 16B

  // fragment addressing (verified formula; k-base now wave-uniform s*32)
  const int frow = lane & 15;
  const int fk = (lane >> 4) * 8;
  const int fsw = frow & 7;
  const int swk = ((((s << 5) + fk) >> 3) ^ fsw) * 8;   // this wave's k-slice offset

  f32x4_t acc[8][4] = {};

#define STAGE_A(b_, i_, kt_) \
  __builtin_amdgcn_global_load_lds( \
      (const __attribute__((address_space(1))) void*)(gA + (size_t)(i_) * 64 * KTOT + (size_t)(kt_) * BK), \
      (__attribute__((address_space(3))) void*)(smem + (b_) * LDSBUF + (i_) * 8192 + wb), 16, 0, 0)
#define STAGE_B(b_, i_, kt_) \
  __builtin_amdgcn_global_load_lds( \
      (const __attribute__((address_space(1))) void*)(gB + (size_t)(i_) * 64 * KTOT + (size_t)(kt_) * BK), \
      (__attribute__((address_space(3))) void*)(smem + (b_) * LDSBUF + LDSA + (i_) * 8192 + wb), 16, 0, 0)

  // prologue: tile 0 -> buf0, tile 1 -> buf1 (12 loads in flight)
  STAGE_A(0, 0, 0); STAGE_A(0, 1, 0); STAGE_A(0, 2, 0); STAGE_A(0, 3, 0);
  STAGE_B(0, 0, 0); STAGE_B(0, 1, 0);
  STAGE_A(1, 0, 1); STAGE_A(1, 1, 1); STAGE_A(1, 2, 1); STAGE_A(1, 3, 1);
  STAGE_B(1, 0, 1); STAGE_B(1, 1, 1);
  asm volatile("s_waitcnt vmcnt(6)" ::: "memory");   // tile 0 resident
  __builtin_amdgcn_s_barrier();

  int cb = 0;
  for (int kt = 0; kt < NT; ++kt) {
    const bf16* sAc = (const bf16*)(smem + cb * LDSBUF);
    const bf16* sBc = (const bf16*)(smem + cb * LDSBUF + LDSA);
    const int pb = (cb == 0) ? 2 : cb - 1;           // (kt+2)%3
    const bool pf = kt < NT - 2;

    // stages for tile kt+2 (vm-only; earliest issue = max slack)
    if (pf) {
      STAGE_A(pb, 0, kt + 2); STAGE_A(pb, 1, kt + 2);
      STAGE_A(pb, 2, kt + 2); STAGE_A(pb, 3, kt + 2);
      STAGE_B(pb, 0, kt + 2); STAGE_B(pb, 1, kt + 2);
    }

    bf16x8_t a_lo[4], a_hi[4], bfr[4];
    // ---- read group 0: a[0..3] + b[0..3] (oldest 8 in lgkm queue) ----
    #pragma unroll
    for (int i = 0; i < 4; ++i) {
      a_lo[i] = *(const bf16x8_t*)(sAc + (wm + i * 16 + frow) * BK + swk);
      bfr[i]  = *(const bf16x8_t*)(sBc + (wn + i * 16 + frow) * BK + swk);
    }
    __builtin_amdgcn_sched_barrier(0);   // pin group boundary (lgkm(4) semantics)
    // ---- read group 1: a[4..7] (newest 4) ----
    #pragma unroll
    for (int i = 0; i < 4; ++i)
      a_hi[i] = *(const bf16x8_t*)(sAc + (wm + 64 + i * 16 + frow) * BK + swk);
    asm volatile("s_waitcnt lgkmcnt(4)" ::: "memory");  // group 0 retired
    __builtin_amdgcn_sched_barrier(0);
    __builtin_amdgcn_s_setprio(1);
    #pragma unroll
    for (int i = 0; i < 4; ++i)
      #pragma unroll
      for (int j = 0; j < 4; ++j)
        acc[i][j] = __builtin_amdgcn_mfma_f32_16x16x32_bf16(a_lo[i], bfr[j], acc[i][j], 0, 0, 0);
    __builtin_amdgcn_s_setprio(0);
    asm volatile("s_waitcnt lgkmcnt(0)" ::: "memory");  // group 1 (drained under MFMA0)
    __builtin_amdgcn_sched_barrier(0);
    __builtin_amdgcn_s_setprio(1);
    #pragma unroll
    for (int i = 0; i < 4; ++i)
      #pragma unroll
      for (int j = 0; j < 4; ++j)
        acc[i + 4][j] = __builtin_amdgcn_mfma_f32_16x16x32_bf16(a_hi[i], bfr[j], acc[i + 4][j], 0, 0, 0);
    __builtin_amdgcn_s_setprio(0);
    // boundary: counted wait (tile kt+1's stages older than the 6 just issued)
    if (pf) { asm volatile("s_waitcnt vmcnt(6)" ::: "memory"); }
    else    { asm volatile("s_waitcnt vmcnt(0)" ::: "memory"); }
    __builtin_amdgcn_s_barrier();

    cb = (cb == 2) ? 0 : cb + 1;
  }

  // ---- epilogue: merge k-slice pairs via LDS (ring no longer live) ----
  // s=1 waves dump acc; s=0 waves add + store. 32KB per quadrant, lane-contiguous
  // 16B slots (conflict-free); 128KB total <= 144KB smem.
  if (s == 1) {
    char* dst = smem + q * 32768;
    #pragma unroll
    for (int i = 0; i < 8; ++i)
      #pragma unroll
      for (int j = 0; j < 4; ++j)
        *(f32x4_t*)(dst + ((i * 4 + j) * 64 + lane) * 16) = acc[i][j];
  }
  __syncthreads();
  if (s == 0) {
    const char* src = smem + q * 32768;
    #pragma unroll
    for (int i = 0; i < 8; ++i)
      #pragma unroll
      for (int j = 0; j < 4; ++j) {
        const f32x4_t p = *(const f32x4_t*)(src + ((i * 4 + j) * 64 + lane) * 16);
        acc[i][j] += p;
      }
    // D mapping col = lane&15, row = (lane>>4)*4 + reg  [m89/m91]
    const int ccol = bc * BN + wn + frow;
    const int crow0 = br * BM + wm + (lane >> 4) * 4;
    #pragma unroll
    for (int i = 0; i < 8; ++i)
      #pragma unroll
      for (int r = 0; r < 4; ++r) {
        float* cp = C + (size_t)(crow0 + i * 16 + r) * OUTF + ccol;
        #pragma unroll
        for (int j = 0; j < 4; ++j)
          cp[j * 16] = acc[i][j][r];
      }
  }
#undef STAGE_A
#undef STAGE_B
}

// ---------------- fallback (ws too small): naive, correctness-only ----------------
__global__ __launch_bounds__(256) void naive_kern(const float* __restrict__ x,
                                                  const float* __restrict__ bw,
                                                  const float* __restrict__ sw,
                                                  const float* __restrict__ ss,
                                                  const float* __restrict__ grid,
                                                  float* __restrict__ out) {
  const int idx = blockIdx.x * 256 + threadIdx.x;  // n*OUTF + o
  const int o = idx & (OUTF - 1);
  const int n = idx >> 10;
  float acc = 0.f;
  for (int i = 0; i < INF; ++i) {
    const float xv = x[n * INF + i];
    const float s = xv / (1.f + __expf(-xv));
    acc += s * bw[o * INF + i];
    const float sc = ss[o * INF + i];
    #pragma unroll
    for (int g = 0; g < 8; ++g) {
      const float gv = grid[i * 8 + g];
      acc += __expf(-fabsf(xv - gv)) * sw[(size_t)(o * INF + i) * 8 + g] * sc;
    }
  }
  out[idx] = acc;
}

extern "C" void kernel_launch(void* const* d_in, const int* in_sizes, int n_in,
                              void* d_out, int out_size, void* d_ws, size_t ws_size,
                              hipStream_t stream) {
  const float* x    = (const float*)d_in[0];
  const float* bw   = (const float*)d_in[1];
  const float* sw   = (const float*)d_in[2];
  const float* ss   = (const float*)d_in[3];
  const float* grid = (const float*)d_in[4];
  float* out = (float*)d_out;

  const size_t needA = (size_t)NTOK * KTOT * sizeof(bf16);  // ~151 MB
  const size_t needB = (size_t)OUTF * KTOT * sizeof(bf16);  // ~19 MB

  if (ws_size >= needA + needB) {
    bf16* A = (bf16*)d_ws;
    bf16* B = (bf16*)((char*)d_ws + needA);
    prep_fused<<<PA + PB, 256, 0, stream>>>(x, bw, sw, ss, A, B);
    dim3 g(OUTF / BN, NTOK / BM);  // (8, 32) = 256 blocks = 1/CU
    gemm_bt2<<<g, 512, 0, stream>>>(A, B, out);
  } else {
    naive_kern<<<(NTOK * OUTF) / 256, 256, 0, stream>>>(x, bw, sw, ss, grid, out);
  }
}